// Round 1
// baseline (139.739 us; speedup 1.0000x reference)
//
#include <hip/hip_runtime.h>
#include <math.h>

// Problem: feats (16384, 1024) fp32.
//   pair_sum = N * sum(x*x) - dot(colsum, colsum); out = exp(-pair_sum/count)
// Pure reduction: 64 MiB read -> 1 float. Memory-bound; floor ~10.6 us @ 6.3 TB/s.

#define DIMC 1024  // feature dim (constant per reference)

// ws layout (floats): [0..DIMC-1] column sums, [DIMC] total squared norm.
__global__ __launch_bounds__(256) void zero_ws_kernel(float* __restrict__ ws) {
    int idx = blockIdx.x * 256 + threadIdx.x;
    if (idx <= DIMC) ws[idx] = 0.0f;
}

// 256 threads/block: thread t owns columns 4t..4t+3 (one float4 per row).
// Consecutive threads -> consecutive float4 -> fully coalesced 4 KB/row/block.
__global__ __launch_bounds__(256) void partial_kernel(const float* __restrict__ feats,
                                                      float* __restrict__ ws,
                                                      int nrows) {
    const int t = threadIdx.x;
    const int col4 = t * 4;
    float4 csum = make_float4(0.f, 0.f, 0.f, 0.f);
    float sq = 0.f;
    for (int row = blockIdx.x; row < nrows; row += gridDim.x) {
        const float4 v = *reinterpret_cast<const float4*>(feats + (size_t)row * DIMC + col4);
        csum.x += v.x; csum.y += v.y; csum.z += v.z; csum.w += v.w;
        sq += v.x * v.x + v.y * v.y + v.z * v.z + v.w * v.w;
    }
    // Column partials: each column owned by exactly one thread per block.
    atomicAdd(&ws[col4 + 0], csum.x);
    atomicAdd(&ws[col4 + 1], csum.y);
    atomicAdd(&ws[col4 + 2], csum.z);
    atomicAdd(&ws[col4 + 3], csum.w);
    // Squared-norm partial: wave shuffle reduce (wave=64), then LDS across 4 waves.
    for (int off = 32; off > 0; off >>= 1) sq += __shfl_down(sq, off, 64);
    __shared__ float wsum[4];
    const int lane = t & 63, wave = t >> 6;
    if (lane == 0) wsum[wave] = sq;
    __syncthreads();
    if (t == 0) {
        atomicAdd(&ws[DIMC], wsum[0] + wsum[1] + wsum[2] + wsum[3]);
    }
}

__global__ __launch_bounds__(1024) void finalize_kernel(const float* __restrict__ ws,
                                                        float* __restrict__ out,
                                                        int nrows) {
    const int t = threadIdx.x;  // 1024 threads = 16 waves; one thread per column
    float c = ws[t];
    float s = c * c;
    for (int off = 32; off > 0; off >>= 1) s += __shfl_down(s, off, 64);
    __shared__ float wsum[16];
    const int lane = t & 63, wave = t >> 6;
    if (lane == 0) wsum[wave] = s;
    __syncthreads();
    if (t == 0) {
        float dot = 0.f;
        #pragma unroll
        for (int i = 0; i < 16; ++i) dot += wsum[i];
        const double sq_total = (double)ws[DIMC];
        const double pair = (double)nrows * sq_total - (double)dot;
        const double count = (double)nrows * (double)(nrows - 1) * 0.5;
        out[0] = (float)exp(-pair / count);
    }
}

extern "C" void kernel_launch(void* const* d_in, const int* in_sizes, int n_in,
                              void* d_out, int out_size, void* d_ws, size_t ws_size,
                              hipStream_t stream) {
    const float* feats = (const float*)d_in[0];
    float* out = (float*)d_out;
    float* ws = (float*)d_ws;
    const int nrows = in_sizes[0] / DIMC;  // 16384

    zero_ws_kernel<<<(DIMC + 256) / 256, 256, 0, stream>>>(ws);
    partial_kernel<<<512, 256, 0, stream>>>(feats, ws, nrows);
    finalize_kernel<<<1, 1024, 0, stream>>>(ws, out, nrows);
}

// Round 2
// 109.351 us; speedup vs baseline: 1.2779x; 1.2779x over previous
//
#include <hip/hip_runtime.h>
#include <math.h>

// feats (16384, 1024) fp32 -> scalar. Memory-bound reduction, floor ~10.6 us @ 6.3 TB/s.
// Identity: pair_sum = N*sum(x*x) - dot(colsum,colsum); out = exp(-pair_sum/count).
//
// R1 lesson: dynamic-trip grid-stride loop compiled to VGPR=8, zero ILP ->
// latency-bound at 604 GB/s; and 524K atomicAdds wrote 8.4 MB RMW to HBM.
// R2: compile-time unroll-16 (16 KB in flight/wave), 1024 blocks (16 waves/CU),
// per-block partials stored plain+coalesced to ws, small tree reduce after.

#define DIMC 1024
#define GRID_A 1024   // stage-1 blocks (4 per CU)
#define RED_BLOCKS 64 // stage-2 blocks

// ws layout (floats): [0..DIMC-1] colsum, [DIMC] sq total, [2048 ...] P[GRID_A][DIMC]
__global__ __launch_bounds__(256) void zero_ws_kernel(float* __restrict__ ws) {
    int idx = blockIdx.x * 256 + threadIdx.x;
    if (idx <= DIMC) ws[idx] = 0.0f;
}

// ---------- Path A: partial sums -> plain stores ----------
__global__ __launch_bounds__(256) void partial_store_kernel(const float* __restrict__ feats,
                                                            float* __restrict__ P,
                                                            float* __restrict__ sq_total,
                                                            int rows_per_block) {
    const int t = threadIdx.x;
    const int col4 = t * 4;  // thread owns 4 consecutive columns -> coalesced float4
    const float* base = feats + (size_t)blockIdx.x * rows_per_block * DIMC + col4;
    float4 csum = make_float4(0.f, 0.f, 0.f, 0.f);
    float sq = 0.f;
    int r = 0;
    for (; r + 16 <= rows_per_block; r += 16) {
        float4 v[16];
        #pragma unroll
        for (int j = 0; j < 16; ++j)
            v[j] = *reinterpret_cast<const float4*>(base + (size_t)(r + j) * DIMC);
        #pragma unroll
        for (int j = 0; j < 16; ++j) {
            csum.x += v[j].x; csum.y += v[j].y; csum.z += v[j].z; csum.w += v[j].w;
            sq += v[j].x * v[j].x + v[j].y * v[j].y + v[j].z * v[j].z + v[j].w * v[j].w;
        }
    }
    for (; r < rows_per_block; ++r) {  // remainder (unused at 16384 rows)
        float4 v = *reinterpret_cast<const float4*>(base + (size_t)r * DIMC);
        csum.x += v.x; csum.y += v.y; csum.z += v.z; csum.w += v.w;
        sq += v.x * v.x + v.y * v.y + v.z * v.z + v.w * v.w;
    }
    // Plain coalesced store of this block's column partials (no atomics).
    *reinterpret_cast<float4*>(P + (size_t)blockIdx.x * DIMC + col4) = csum;
    // sq: wave shuffle reduce, cross-wave via LDS, one atomic per block.
    for (int off = 32; off > 0; off >>= 1) sq += __shfl_down(sq, off, 64);
    __shared__ float wsum[4];
    const int lane = t & 63, wave = t >> 6;
    if (lane == 0) wsum[wave] = sq;
    __syncthreads();
    if (t == 0) atomicAdd(sq_total, wsum[0] + wsum[1] + wsum[2] + wsum[3]);
}

// Reduce P[GRID_A][DIMC] over blocks: 64 blocks, each sums 16 partial rows,
// then 64-contender atomics into colsum.
__global__ __launch_bounds__(256) void colreduce_kernel(const float* __restrict__ P,
                                                        float* __restrict__ colsum,
                                                        int chunks_per_block) {
    const int t = threadIdx.x;
    const int col4 = t * 4;
    const float* base = P + (size_t)blockIdx.x * chunks_per_block * DIMC + col4;
    float4 acc = make_float4(0.f, 0.f, 0.f, 0.f);
    #pragma unroll 4
    for (int i = 0; i < chunks_per_block; ++i) {
        float4 v = *reinterpret_cast<const float4*>(base + (size_t)i * DIMC);
        acc.x += v.x; acc.y += v.y; acc.z += v.z; acc.w += v.w;
    }
    atomicAdd(&colsum[col4 + 0], acc.x);
    atomicAdd(&colsum[col4 + 1], acc.y);
    atomicAdd(&colsum[col4 + 2], acc.z);
    atomicAdd(&colsum[col4 + 3], acc.w);
}

// ---------- Path B fallback (tiny ws): R1's working atomic kernel ----------
__global__ __launch_bounds__(256) void partial_atomic_kernel(const float* __restrict__ feats,
                                                             float* __restrict__ ws,
                                                             int nrows) {
    const int t = threadIdx.x;
    const int col4 = t * 4;
    float4 csum = make_float4(0.f, 0.f, 0.f, 0.f);
    float sq = 0.f;
    for (int row = blockIdx.x; row < nrows; row += gridDim.x) {
        const float4 v = *reinterpret_cast<const float4*>(feats + (size_t)row * DIMC + col4);
        csum.x += v.x; csum.y += v.y; csum.z += v.z; csum.w += v.w;
        sq += v.x * v.x + v.y * v.y + v.z * v.z + v.w * v.w;
    }
    atomicAdd(&ws[col4 + 0], csum.x);
    atomicAdd(&ws[col4 + 1], csum.y);
    atomicAdd(&ws[col4 + 2], csum.z);
    atomicAdd(&ws[col4 + 3], csum.w);
    for (int off = 32; off > 0; off >>= 1) sq += __shfl_down(sq, off, 64);
    __shared__ float wsum[4];
    const int lane = t & 63, wave = t >> 6;
    if (lane == 0) wsum[wave] = sq;
    __syncthreads();
    if (t == 0) atomicAdd(&ws[DIMC], wsum[0] + wsum[1] + wsum[2] + wsum[3]);
}

__global__ __launch_bounds__(1024) void finalize_kernel(const float* __restrict__ ws,
                                                        float* __restrict__ out,
                                                        int nrows) {
    const int t = threadIdx.x;  // one thread per column
    float c = ws[t];
    float s = c * c;
    for (int off = 32; off > 0; off >>= 1) s += __shfl_down(s, off, 64);
    __shared__ float wsum[16];
    const int lane = t & 63, wave = t >> 6;
    if (lane == 0) wsum[wave] = s;
    __syncthreads();
    if (t == 0) {
        float dot = 0.f;
        #pragma unroll
        for (int i = 0; i < 16; ++i) dot += wsum[i];
        const double sq_total = (double)ws[DIMC];
        const double pair = (double)nrows * sq_total - (double)dot;
        const double count = (double)nrows * (double)(nrows - 1) * 0.5;
        out[0] = (float)exp(-pair / count);
    }
}

extern "C" void kernel_launch(void* const* d_in, const int* in_sizes, int n_in,
                              void* d_out, int out_size, void* d_ws, size_t ws_size,
                              hipStream_t stream) {
    const float* feats = (const float*)d_in[0];
    float* out = (float*)d_out;
    float* ws = (float*)d_ws;
    const int nrows = in_sizes[0] / DIMC;  // 16384

    float* colsum = ws;
    float* sq_total = ws + DIMC;
    float* P = ws + 2048;
    const size_t need_a = (2048 + (size_t)GRID_A * DIMC) * sizeof(float);  // ~4.2 MB

    zero_ws_kernel<<<(DIMC + 256) / 256, 256, 0, stream>>>(ws);
    if (ws_size >= need_a && nrows % GRID_A == 0) {
        partial_store_kernel<<<GRID_A, 256, 0, stream>>>(feats, P, sq_total, nrows / GRID_A);
        colreduce_kernel<<<RED_BLOCKS, 256, 0, stream>>>(P, colsum, GRID_A / RED_BLOCKS);
    } else {
        partial_atomic_kernel<<<512, 256, 0, stream>>>(feats, ws, nrows);
    }
    finalize_kernel<<<1, 1024, 0, stream>>>(ws, out, nrows);
}

// Round 3
// 101.785 us; speedup vs baseline: 1.3729x; 1.0743x over previous
//
#include <hip/hip_runtime.h>
#include <math.h>

// feats (16384, 1024) fp32 -> scalar. Memory-bound reduction.
//   pair = N*sum(x*x) - dot(colsum,colsum); out = exp(-pair/count)
//
// Harness-fixed per-replay cost (measured R2): 256MB ws poison fill = 41 us
// @6.5 TB/s + ~21 us input restore -> ~63 us floor we cannot touch.
// R3: no atomics, no zero-init on main path, 3-kernel tree, nontemporal
// streaming loads (input read exactly once; L2 caching is pollution).

#define DIMC 1024
#define GRID_A 1024   // stage-1 blocks; rows/block = 16384/1024 = 16
#define ROWS_A 16
#define RED_BLOCKS 64 // stage-2 blocks; each reduces 16 P-rows

typedef float vf4 __attribute__((ext_vector_type(4)));

// ---------------- main path (nrows == 16384), no atomics ----------------
// ws layout (floats): P[GRID_A][DIMC] | SQ[GRID_A] | P2[RED_BLOCKS][DIMC]

__global__ __launch_bounds__(256) void stage1_kernel(const float* __restrict__ feats,
                                                     float* __restrict__ P,
                                                     float* __restrict__ SQ) {
    const int t = threadIdx.x;          // owns float4-column t (cols 4t..4t+3)
    const int b = blockIdx.x;
    const vf4* base = reinterpret_cast<const vf4*>(feats) + (size_t)b * (ROWS_A * 256) + t;
    vf4 v[ROWS_A];
    #pragma unroll
    for (int j = 0; j < ROWS_A; ++j)      // 16 independent 16B loads in flight
        v[j] = __builtin_nontemporal_load(base + (size_t)j * 256);
    vf4 csum = v[0];
    float sq = v[0].x * v[0].x + v[0].y * v[0].y + v[0].z * v[0].z + v[0].w * v[0].w;
    #pragma unroll
    for (int j = 1; j < ROWS_A; ++j) {
        csum += v[j];
        sq += v[j].x * v[j].x + v[j].y * v[j].y + v[j].z * v[j].z + v[j].w * v[j].w;
    }
    reinterpret_cast<vf4*>(P)[(size_t)b * 256 + t] = csum;  // plain coalesced store
    for (int off = 32; off > 0; off >>= 1) sq += __shfl_down(sq, off, 64);
    __shared__ float wsum[4];
    if ((t & 63) == 0) wsum[t >> 6] = sq;
    __syncthreads();
    if (t == 0) SQ[b] = wsum[0] + wsum[1] + wsum[2] + wsum[3];  // plain store
}

// 64 blocks: block r sums P rows 16r..16r+15 -> P2[r][*]. Plain stores.
__global__ __launch_bounds__(256) void stage2_kernel(const float* __restrict__ P,
                                                     float* __restrict__ P2) {
    const int t = threadIdx.x;
    const int r = blockIdx.x;
    const vf4* base = reinterpret_cast<const vf4*>(P) + (size_t)r * 16 * 256 + t;
    vf4 acc = base[0];
    #pragma unroll
    for (int i = 1; i < 16; ++i) acc += base[(size_t)i * 256];
    reinterpret_cast<vf4*>(P2)[(size_t)r * 256 + t] = acc;
}

// 1 block, 1024 threads: final colsum over P2 (64 coalesced 4KB rows), dot,
// SQ reduce, scalar math.
__global__ __launch_bounds__(1024) void finalize3_kernel(const float* __restrict__ P2,
                                                         const float* __restrict__ SQ,
                                                         float* __restrict__ out,
                                                         int nrows) {
    const int t = threadIdx.x;
    float c = 0.f;
    #pragma unroll 8
    for (int r = 0; r < RED_BLOCKS; ++r) c += P2[(size_t)r * DIMC + t];
    float s = c * c;
    float q = SQ[t];  // GRID_A == 1024 == blockDim
    for (int off = 32; off > 0; off >>= 1) {
        s += __shfl_down(s, off, 64);
        q += __shfl_down(q, off, 64);
    }
    __shared__ float sdot[16], ssq[16];
    const int lane = t & 63, wave = t >> 6;
    if (lane == 0) { sdot[wave] = s; ssq[wave] = q; }
    __syncthreads();
    if (t == 0) {
        float dot = 0.f, sqt = 0.f;
        #pragma unroll
        for (int i = 0; i < 16; ++i) { dot += sdot[i]; sqt += ssq[i]; }
        const double pair = (double)nrows * (double)sqt - (double)dot;
        const double count = (double)nrows * (double)(nrows - 1) * 0.5;
        out[0] = (float)exp(-pair / count);
    }
}

// ---------------- fallback path (generic nrows): R1 atomic version ----------------
__global__ __launch_bounds__(256) void zero_ws_kernel(float* __restrict__ ws) {
    int idx = blockIdx.x * 256 + threadIdx.x;
    if (idx <= DIMC) ws[idx] = 0.0f;
}

__global__ __launch_bounds__(256) void partial_atomic_kernel(const float* __restrict__ feats,
                                                             float* __restrict__ ws,
                                                             int nrows) {
    const int t = threadIdx.x;
    const int col4 = t * 4;
    float4 csum = make_float4(0.f, 0.f, 0.f, 0.f);
    float sq = 0.f;
    for (int row = blockIdx.x; row < nrows; row += gridDim.x) {
        const float4 v = *reinterpret_cast<const float4*>(feats + (size_t)row * DIMC + col4);
        csum.x += v.x; csum.y += v.y; csum.z += v.z; csum.w += v.w;
        sq += v.x * v.x + v.y * v.y + v.z * v.z + v.w * v.w;
    }
    atomicAdd(&ws[col4 + 0], csum.x);
    atomicAdd(&ws[col4 + 1], csum.y);
    atomicAdd(&ws[col4 + 2], csum.z);
    atomicAdd(&ws[col4 + 3], csum.w);
    for (int off = 32; off > 0; off >>= 1) sq += __shfl_down(sq, off, 64);
    __shared__ float wsum[4];
    const int lane = t & 63, wave = t >> 6;
    if (lane == 0) wsum[wave] = sq;
    __syncthreads();
    if (t == 0) atomicAdd(&ws[DIMC], wsum[0] + wsum[1] + wsum[2] + wsum[3]);
}

__global__ __launch_bounds__(1024) void finalize_ws_kernel(const float* __restrict__ ws,
                                                           float* __restrict__ out,
                                                           int nrows) {
    const int t = threadIdx.x;
    float c = ws[t];
    float s = c * c;
    for (int off = 32; off > 0; off >>= 1) s += __shfl_down(s, off, 64);
    __shared__ float wsum[16];
    const int lane = t & 63, wave = t >> 6;
    if (lane == 0) wsum[wave] = s;
    __syncthreads();
    if (t == 0) {
        float dot = 0.f;
        #pragma unroll
        for (int i = 0; i < 16; ++i) dot += wsum[i];
        const double pair = (double)nrows * (double)ws[DIMC] - (double)dot;
        const double count = (double)nrows * (double)(nrows - 1) * 0.5;
        out[0] = (float)exp(-pair / count);
    }
}

extern "C" void kernel_launch(void* const* d_in, const int* in_sizes, int n_in,
                              void* d_out, int out_size, void* d_ws, size_t ws_size,
                              hipStream_t stream) {
    const float* feats = (const float*)d_in[0];
    float* out = (float*)d_out;
    float* ws = (float*)d_ws;
    const int nrows = in_sizes[0] / DIMC;

    float* P = ws;                                   // GRID_A*DIMC floats
    float* SQ = P + (size_t)GRID_A * DIMC;           // GRID_A floats
    float* P2 = SQ + GRID_A;                         // RED_BLOCKS*DIMC floats
    const size_t need = ((size_t)GRID_A * DIMC + GRID_A + (size_t)RED_BLOCKS * DIMC) * sizeof(float);

    if (nrows == GRID_A * ROWS_A && ws_size >= need) {
        stage1_kernel<<<GRID_A, 256, 0, stream>>>(feats, P, SQ);
        stage2_kernel<<<RED_BLOCKS, 256, 0, stream>>>(P, P2);
        finalize3_kernel<<<1, 1024, 0, stream>>>(P2, SQ, out, nrows);
    } else {
        zero_ws_kernel<<<(DIMC + 256) / 256, 256, 0, stream>>>(ws);
        partial_atomic_kernel<<<512, 256, 0, stream>>>(feats, ws, nrows);
        finalize_ws_kernel<<<1, 1024, 0, stream>>>(ws, out, nrows);
    }
}

// Round 4
// 95.188 us; speedup vs baseline: 1.4680x; 1.0693x over previous
//
#include <hip/hip_runtime.h>
#include <math.h>

// feats (16384, 1024) fp32 -> scalar. Memory-bound reduction.
//   pair = N*sum(x*x) - dot(colsum,colsum); out = exp(-pair/count)
//
// Harness-fixed per-replay cost: ws poison fill (42 us @6.5 TB/s, measured) +
// 64 MiB input restore (~20 us) -> ~63-66 us floor.
// R3 post-mortem: stage1 ~30 us (~2.2 TB/s) with nontemporal loads.
// R4 theory: nt bits bypass L2/L3 retention; the input was JUST written by the
// harness restore copy and is resident in the 256 MiB Infinity Cache. Plain
// loads should hit L3 and push stage1 toward ~10 us. Single-variable A/B.

#define DIMC 1024
#define GRID_A 1024   // stage-1 blocks; rows/block = 16384/1024 = 16
#define ROWS_A 16
#define RED_BLOCKS 64 // stage-2 blocks; each reduces 16 P-rows

typedef float vf4 __attribute__((ext_vector_type(4)));

// ---------------- main path (nrows == 16384), no atomics ----------------
// ws layout (floats): P[GRID_A][DIMC] | SQ[GRID_A] | P2[RED_BLOCKS][DIMC]

__global__ __launch_bounds__(256) void stage1_kernel(const float* __restrict__ feats,
                                                     float* __restrict__ P,
                                                     float* __restrict__ SQ) {
    const int t = threadIdx.x;          // owns float4-column t (cols 4t..4t+3)
    const int b = blockIdx.x;
    const vf4* base = reinterpret_cast<const vf4*>(feats) + (size_t)b * (ROWS_A * 256) + t;
    vf4 v[ROWS_A];
    #pragma unroll
    for (int j = 0; j < ROWS_A; ++j)      // 16 independent 16B loads in flight
        v[j] = base[(size_t)j * 256];     // PLAIN loads (R4 change: no nt)
    vf4 csum = v[0];
    float sq = v[0].x * v[0].x + v[0].y * v[0].y + v[0].z * v[0].z + v[0].w * v[0].w;
    #pragma unroll
    for (int j = 1; j < ROWS_A; ++j) {
        csum += v[j];
        sq += v[j].x * v[j].x + v[j].y * v[j].y + v[j].z * v[j].z + v[j].w * v[j].w;
    }
    reinterpret_cast<vf4*>(P)[(size_t)b * 256 + t] = csum;  // plain coalesced store
    for (int off = 32; off > 0; off >>= 1) sq += __shfl_down(sq, off, 64);
    __shared__ float wsum[4];
    if ((t & 63) == 0) wsum[t >> 6] = sq;
    __syncthreads();
    if (t == 0) SQ[b] = wsum[0] + wsum[1] + wsum[2] + wsum[3];  // plain store
}

// 64 blocks: block r sums P rows 16r..16r+15 -> P2[r][*]. Plain stores.
__global__ __launch_bounds__(256) void stage2_kernel(const float* __restrict__ P,
                                                     float* __restrict__ P2) {
    const int t = threadIdx.x;
    const int r = blockIdx.x;
    const vf4* base = reinterpret_cast<const vf4*>(P) + (size_t)r * 16 * 256 + t;
    vf4 acc = base[0];
    #pragma unroll
    for (int i = 1; i < 16; ++i) acc += base[(size_t)i * 256];
    reinterpret_cast<vf4*>(P2)[(size_t)r * 256 + t] = acc;
}

// 1 block, 1024 threads: final colsum over P2 (64 coalesced 4KB rows), dot,
// SQ reduce, scalar math.
__global__ __launch_bounds__(1024) void finalize3_kernel(const float* __restrict__ P2,
                                                         const float* __restrict__ SQ,
                                                         float* __restrict__ out,
                                                         int nrows) {
    const int t = threadIdx.x;
    float c = 0.f;
    #pragma unroll 8
    for (int r = 0; r < RED_BLOCKS; ++r) c += P2[(size_t)r * DIMC + t];
    float s = c * c;
    float q = SQ[t];  // GRID_A == 1024 == blockDim
    for (int off = 32; off > 0; off >>= 1) {
        s += __shfl_down(s, off, 64);
        q += __shfl_down(q, off, 64);
    }
    __shared__ float sdot[16], ssq[16];
    const int lane = t & 63, wave = t >> 6;
    if (lane == 0) { sdot[wave] = s; ssq[wave] = q; }
    __syncthreads();
    if (t == 0) {
        float dot = 0.f, sqt = 0.f;
        #pragma unroll
        for (int i = 0; i < 16; ++i) { dot += sdot[i]; sqt += ssq[i]; }
        const double pair = (double)nrows * (double)sqt - (double)dot;
        const double count = (double)nrows * (double)(nrows - 1) * 0.5;
        out[0] = (float)exp(-pair / count);
    }
}

// ---------------- fallback path (generic nrows): R1 atomic version ----------------
__global__ __launch_bounds__(256) void zero_ws_kernel(float* __restrict__ ws) {
    int idx = blockIdx.x * 256 + threadIdx.x;
    if (idx <= DIMC) ws[idx] = 0.0f;
}

__global__ __launch_bounds__(256) void partial_atomic_kernel(const float* __restrict__ feats,
                                                             float* __restrict__ ws,
                                                             int nrows) {
    const int t = threadIdx.x;
    const int col4 = t * 4;
    float4 csum = make_float4(0.f, 0.f, 0.f, 0.f);
    float sq = 0.f;
    for (int row = blockIdx.x; row < nrows; row += gridDim.x) {
        const float4 v = *reinterpret_cast<const float4*>(feats + (size_t)row * DIMC + col4);
        csum.x += v.x; csum.y += v.y; csum.z += v.z; csum.w += v.w;
        sq += v.x * v.x + v.y * v.y + v.z * v.z + v.w * v.w;
    }
    atomicAdd(&ws[col4 + 0], csum.x);
    atomicAdd(&ws[col4 + 1], csum.y);
    atomicAdd(&ws[col4 + 2], csum.z);
    atomicAdd(&ws[col4 + 3], csum.w);
    for (int off = 32; off > 0; off >>= 1) sq += __shfl_down(sq, off, 64);
    __shared__ float wsum[4];
    const int lane = t & 63, wave = t >> 6;
    if (lane == 0) wsum[wave] = sq;
    __syncthreads();
    if (t == 0) atomicAdd(&ws[DIMC], wsum[0] + wsum[1] + wsum[2] + wsum[3]);
}

__global__ __launch_bounds__(1024) void finalize_ws_kernel(const float* __restrict__ ws,
                                                           float* __restrict__ out,
                                                           int nrows) {
    const int t = threadIdx.x;
    float c = ws[t];
    float s = c * c;
    for (int off = 32; off > 0; off >>= 1) s += __shfl_down(s, off, 64);
    __shared__ float wsum[16];
    const int lane = t & 63, wave = t >> 6;
    if (lane == 0) wsum[wave] = s;
    __syncthreads();
    if (t == 0) {
        float dot = 0.f;
        #pragma unroll
        for (int i = 0; i < 16; ++i) dot += wsum[i];
        const double pair = (double)nrows * (double)ws[DIMC] - (double)dot;
        const double count = (double)nrows * (double)(nrows - 1) * 0.5;
        out[0] = (float)exp(-pair / count);
    }
}

extern "C" void kernel_launch(void* const* d_in, const int* in_sizes, int n_in,
                              void* d_out, int out_size, void* d_ws, size_t ws_size,
                              hipStream_t stream) {
    const float* feats = (const float*)d_in[0];
    float* out = (float*)d_out;
    float* ws = (float*)d_ws;
    const int nrows = in_sizes[0] / DIMC;

    float* P = ws;                                   // GRID_A*DIMC floats
    float* SQ = P + (size_t)GRID_A * DIMC;           // GRID_A floats
    float* P2 = SQ + GRID_A;                         // RED_BLOCKS*DIMC floats
    const size_t need = ((size_t)GRID_A * DIMC + GRID_A + (size_t)RED_BLOCKS * DIMC) * sizeof(float);

    if (nrows == GRID_A * ROWS_A && ws_size >= need) {
        stage1_kernel<<<GRID_A, 256, 0, stream>>>(feats, P, SQ);
        stage2_kernel<<<RED_BLOCKS, 256, 0, stream>>>(P, P2);
        finalize3_kernel<<<1, 1024, 0, stream>>>(P2, SQ, out, nrows);
    } else {
        zero_ws_kernel<<<(DIMC + 256) / 256, 256, 0, stream>>>(ws);
        partial_atomic_kernel<<<512, 256, 0, stream>>>(feats, ws, nrows);
        finalize_ws_kernel<<<1, 1024, 0, stream>>>(ws, out, nrows);
    }
}